// Round 6
// baseline (574.701 us; speedup 1.0000x reference)
//
#include <hip/hip_runtime.h>
#include <stdint.h>

#define D_IN 2048
#define D_H  512
#define NCH 8               // k-chunks of 256
#define BM  16              // rows per block (4 waves x 4 rows)

// Pack sign bits of W, transposed, in the permuted bit order the x-pack
// produces: word w = ch*4 + j (ch=0..7), bit p  <->  W[ch*256 + 4p + j][c].
__global__ __launch_bounds__(512) void pack_w_kernel(
    const float* __restrict__ W, unsigned long long* __restrict__ wb) {
  const int w = blockIdx.x;   // 0..31
  const int c = threadIdx.x;  // 0..511
  const int ch = w >> 2;
  const int j  = w & 3;
  unsigned long long bits = 0ull;
#pragma unroll 16
  for (int p = 0; p < 64; ++p) {
    float v = W[(size_t)(ch * 256 + 4 * p + j) * D_H + c];
    bits |= (unsigned long long)(v < 0.0f) << p;
  }
  wb[(size_t)w * D_H + c] = bits;
}

// global -> LDS direct DMA, 16 B per lane. LDS dest = uniform base + lane*16.
#define GLOAD_LDS16(gsrc, ldst)                                            \
  __builtin_amdgcn_global_load_lds(                                        \
      (const __attribute__((address_space(1))) void*)(gsrc),               \
      (__attribute__((address_space(3))) void*)(ldst), 16, 0, 0)

// Binary GEMM. W-bits double-buffered in LDS via global_load_lds (no staging
// registers, no ds_write). X sign bits live in SGPRs via __ballot (wave owns
// its 4 rows). Per iter: issue W-lds(ch+1) + X(ch+1), compute ch from LDS
// (lgkm waits only), ballots (vmcnt drain lands after compute), one barrier.
__global__ __launch_bounds__(256, 2) void bgemm_kernel(
    const float* __restrict__ X,
    const unsigned long long* __restrict__ wb,
    const float* __restrict__ b, const float* __restrict__ beta,
    const float* __restrict__ mm, const float* __restrict__ mv,
    float* __restrict__ out) {
  __shared__ unsigned long long wlds[2][4][512];  // 32 KB

  const int tid = threadIdx.x;
  const int wv  = tid >> 6;   // wave 0..3: stages word wv, owns rows m0..m0+3
  const int l   = tid & 63;
  const size_t m0 = (size_t)blockIdx.x * BM + (size_t)wv * 4;
  const float4* X4 = (const float4*)X;

  unsigned long long sx[4][4];   // wave-uniform -> SGPR pairs
  float4 v[4];                   // staged X (regs, static idx)

  unsigned acc[4][8];
#pragma unroll
  for (int i = 0; i < 4; ++i)
#pragma unroll
    for (int j = 0; j < 8; ++j) acc[i][j] = 0u;

  // ---- prologue: chunk 0 ----
#pragma unroll
  for (int t = 0; t < 4; ++t)  // wave wv stages its word: 4 x 1KB DMA
    GLOAD_LDS16(wb + (size_t)wv * D_H + t * 128 + 2 * l, &wlds[0][wv][t * 128]);
#pragma unroll
  for (int i = 0; i < 4; ++i) v[i] = X4[(m0 + i) * (D_IN / 4) + l];
#pragma unroll
  for (int i = 0; i < 4; ++i) {
    sx[i][0] = __ballot(v[i].x < 0.0f);
    sx[i][1] = __ballot(v[i].y < 0.0f);
    sx[i][2] = __ballot(v[i].z < 0.0f);
    sx[i][3] = __ballot(v[i].w < 0.0f);
  }
  __syncthreads();

#pragma unroll 2
  for (int ch = 0; ch < NCH; ++ch) {
    const int buf = ch & 1;
    if (ch + 1 < NCH) {
      // W DMA first, X loads second (both issued before compute)
#pragma unroll
      for (int t = 0; t < 4; ++t)
        GLOAD_LDS16(wb + ((size_t)(ch + 1) * 4 + wv) * D_H + t * 128 + 2 * l,
                    &wlds[buf ^ 1][wv][t * 128]);
#pragma unroll
      for (int i = 0; i < 4; ++i)
        v[i] = X4[(m0 + i) * (D_IN / 4) + (size_t)(ch + 1) * 64 + l];
    }

    // ---- compute chunk ch from LDS buf: ds_read_b128, conflict-free ----
#pragma unroll
    for (int w = 0; w < 4; ++w) {
#pragma unroll
      for (int t = 0; t < 4; ++t) {
        const ulonglong2 W2 =
            *(const ulonglong2*)&wlds[buf][w][t * 128 + 2 * l];
#pragma unroll
        for (int i = 0; i < 4; ++i) {
          const unsigned long long s = sx[i][w];
          acc[i][2 * t]     += (unsigned)__popcll(s ^ W2.x);
          acc[i][2 * t + 1] += (unsigned)__popcll(s ^ W2.y);
        }
      }
    }

    if (ch + 1 < NCH) {
      // ballots wait vmcnt(0): loads were issued one full compute phase ago
#pragma unroll
      for (int i = 0; i < 4; ++i) {
        sx[i][0] = __ballot(v[i].x < 0.0f);
        sx[i][1] = __ballot(v[i].y < 0.0f);
        sx[i][2] = __ballot(v[i].z < 0.0f);
        sx[i][3] = __ballot(v[i].w < 0.0f);
      }
      __syncthreads();
    }
  }

  // ---- epilogue: y = (K - 2*diff) + b; out = (y - mean)*rsqrt(var+eps) + beta
#pragma unroll
  for (int t = 0; t < 4; ++t) {
    const int cp = 64 * t + l;  // float2 index; col = 2*cp
    const float2 b2 = ((const float2*)b)[cp];
    const float2 m2 = ((const float2*)mm)[cp];
    const float2 e2 = ((const float2*)beta)[cp];
    const float2 v2 = ((const float2*)mv)[cp];
    const float i0 = rsqrtf(v2.x + 1e-3f);
    const float i1 = rsqrtf(v2.y + 1e-3f);
#pragma unroll
    for (int i = 0; i < 4; ++i) {
      float2 o;
      o.x = ((float)(D_IN - 2 * (int)acc[i][2 * t])     + b2.x - m2.x) * i0 + e2.x;
      o.y = ((float)(D_IN - 2 * (int)acc[i][2 * t + 1]) + b2.y - m2.y) * i1 + e2.y;
      ((float2*)(out + (m0 + i) * D_H))[cp] = o;
    }
  }
}

extern "C" void kernel_launch(void* const* d_in, const int* in_sizes, int n_in,
                              void* d_out, int out_size, void* d_ws, size_t ws_size,
                              hipStream_t stream) {
  const float* X    = (const float*)d_in[0];  // [32768, 2048]
  const float* W    = (const float*)d_in[1];  // [2048, 512]
  const float* b    = (const float*)d_in[2];  // [512]
  const float* beta = (const float*)d_in[3];  // [512]
  const float* mm   = (const float*)d_in[4];  // [512]
  const float* mv   = (const float*)d_in[5];  // [512]
  float* out = (float*)d_out;                 // [32768, 512]

  unsigned long long* wbits = (unsigned long long*)d_ws;  // 128 KB

  pack_w_kernel<<<dim3(32), dim3(D_H), 0, stream>>>(W, wbits);

  const int M = in_sizes[0] / D_IN;  // 32768
  bgemm_kernel<<<dim3(M / BM), dim3(256), 0, stream>>>(X, wbits, b, beta, mm, mv, out);
}

// Round 7
// 174.684 us; speedup vs baseline: 3.2900x; 3.2900x over previous
//
#include <hip/hip_runtime.h>
#include <stdint.h>

#define D_IN 2048
#define D_H  512
#define BM   32
#define KSTEPS 64   // D_IN / 32

typedef __attribute__((ext_vector_type(4)))  int i32x4;
typedef __attribute__((ext_vector_type(16))) int i32x16;

// Wt[n][k] = sign(W[k][n]) as +1/-1 int8 (1 MB). Reads coalesced across n.
__global__ __launch_bounds__(512) void pack_wt_kernel(
    const float* __restrict__ W, char* __restrict__ Wt) {
  const int n  = threadIdx.x;       // 0..511
  const int k0 = blockIdx.x * 32;   // 64 blocks
  uint words[8];
#pragma unroll
  for (int wq = 0; wq < 8; ++wq) {
    uint w = 0x01010101u;  // +1 bytes; negative -> XOR 0xFE -> 0xFF (-1)
#pragma unroll
    for (int j = 0; j < 4; ++j) {
      uint bits = __float_as_uint(W[(size_t)(k0 + wq * 4 + j) * D_H + n]);
      w ^= ((uint)((int)bits >> 31)) & (0xFEu << (8 * j));
    }
    words[wq] = w;
  }
  uint* dst = (uint*)(Wt + (size_t)n * D_IN + k0);
#pragma unroll
  for (int wq = 0; wq < 8; ++wq) dst[wq] = words[wq];
}

__device__ inline uint pack4(float4 v) {
  // byte j = sign(v[j]) ? 0xFF : 0x01  (borrow-free via XOR)
  uint w = 0x01010101u;
  w ^= ((uint)((int)__float_as_uint(v.x) >> 31)) & 0x000000FEu;
  w ^= ((uint)((int)__float_as_uint(v.y) >> 31)) & 0x0000FE00u;
  w ^= ((uint)((int)__float_as_uint(v.z) >> 31)) & 0x00FE0000u;
  w ^= ((uint)((int)__float_as_uint(v.w) >> 31)) & 0xFE000000u;
  return w;
}

// Binary GEMM via v_mfma_i32_32x32x32_i8.
// Block: 32 rows x 512 cols, 4 waves (wave wv owns cols [128wv,128wv+128)).
// A-tile 32x32 i8 in LDS (double-buffered, contiguous = bank-balanced).
// B-frags from global (Wt is 1MB, L2-resident). X issued 2 k-steps ahead;
// B-loads issued before X so MFMA's vmcnt wait leaves X in flight.
__global__ __launch_bounds__(256, 2) void bgemm_kernel(
    const float* __restrict__ X, const char* __restrict__ Wt,
    const float* __restrict__ b, const float* __restrict__ beta,
    const float* __restrict__ mm, const float* __restrict__ mv,
    float* __restrict__ out) {
  __shared__ __align__(16) uint Alds[2][32][8];  // 2 KB

  const int tid = threadIdx.x;
  const int l   = tid & 63;
  const int wv  = tid >> 6;
  const size_t m0 = (size_t)blockIdx.x * BM;
  const int nbase = wv * 128;

  // staging coords: thread t -> row sm, k-word skg (4 k's)
  const int sm = tid >> 3, skg = tid & 7;
  const float4* Xrow = (const float4*)(X + (m0 + sm) * D_IN);  // idx 8s+skg

  // MFMA fragment coords
  const int am = l & 31, ah = l >> 5;
  const char* WtL = Wt + (size_t)(nbase + am) * D_IN + 16 * ah;

  i32x16 acc0, acc1, acc2, acc3;
#pragma unroll
  for (int r = 0; r < 16; ++r) { acc0[r] = 0; acc1[r] = 0; acc2[r] = 0; acc3[r] = 0; }

  // ---- prologue: steps 0,1 in regs; stage step 0 into buf0 ----
  float4 vxA = Xrow[skg];       // step 0
  float4 vxB = Xrow[8 + skg];   // step 1
  Alds[0][sm][skg] = pack4(vxA);
  __syncthreads();

#pragma unroll 1
  for (int s = 0; s < KSTEPS; s += 2) {
    // ===== even body: compute step s from buf0; stage s+1 -> buf1 =====
    {
      const char* wp = WtL + (size_t)s * 32;
      i32x4 b0 = *(const i32x4*)(wp + 0 * 32 * D_IN);  // B loads (oldest)
      i32x4 b1 = *(const i32x4*)(wp + 1 * 32 * D_IN);
      i32x4 b2 = *(const i32x4*)(wp + 2 * 32 * D_IN);
      i32x4 b3 = *(const i32x4*)(wp + 3 * 32 * D_IN);
      if (s + 2 < KSTEPS) vxA = Xrow[8 * (s + 2) + skg];  // X issue (young)
      i32x4 a = *(const i32x4*)&Alds[0][am][4 * ah];
      acc0 = __builtin_amdgcn_mfma_i32_32x32x32_i8(a, b0, acc0, 0, 0, 0);
      acc1 = __builtin_amdgcn_mfma_i32_32x32x32_i8(a, b1, acc1, 0, 0, 0);
      acc2 = __builtin_amdgcn_mfma_i32_32x32x32_i8(a, b2, acc2, 0, 0, 0);
      acc3 = __builtin_amdgcn_mfma_i32_32x32x32_i8(a, b3, acc3, 0, 0, 0);
      Alds[1][sm][skg] = pack4(vxB);  // vxB issued a full body ago
      __syncthreads();
    }
    // ===== odd body: compute step s+1 from buf1; stage s+2 -> buf0 =====
    {
      const char* wp = WtL + (size_t)(s + 1) * 32;
      i32x4 b0 = *(const i32x4*)(wp + 0 * 32 * D_IN);
      i32x4 b1 = *(const i32x4*)(wp + 1 * 32 * D_IN);
      i32x4 b2 = *(const i32x4*)(wp + 2 * 32 * D_IN);
      i32x4 b3 = *(const i32x4*)(wp + 3 * 32 * D_IN);
      if (s + 3 < KSTEPS) vxB = Xrow[8 * (s + 3) + skg];
      i32x4 a = *(const i32x4*)&Alds[1][am][4 * ah];
      acc0 = __builtin_amdgcn_mfma_i32_32x32x32_i8(a, b0, acc0, 0, 0, 0);
      acc1 = __builtin_amdgcn_mfma_i32_32x32x32_i8(a, b1, acc1, 0, 0, 0);
      acc2 = __builtin_amdgcn_mfma_i32_32x32x32_i8(a, b2, acc2, 0, 0, 0);
      acc3 = __builtin_amdgcn_mfma_i32_32x32x32_i8(a, b3, acc3, 0, 0, 0);
      if (s + 2 < KSTEPS) {
        Alds[0][sm][skg] = pack4(vxA);
        __syncthreads();
      }
    }
  }

  // ---- epilogue: out = (dot + b - mean) * rsqrt(var+eps) + beta ----
  // D layout (verified): col = l&31, row = (r&3) + 8*(r>>2) + 4*(l>>5)
  const int rb = 4 * (l >> 5);
#pragma unroll
  for (int nt = 0; nt < 4; ++nt) {
    const i32x16 A = (nt == 0) ? acc0 : (nt == 1) ? acc1 : (nt == 2) ? acc2 : acc3;
    const int c = nbase + nt * 32 + am;
    const float bb  = b[c];
    const float mmc = mm[c];
    const float bec = beta[c];
    const float inv = rsqrtf(mv[c] + 1e-3f);
#pragma unroll
    for (int r = 0; r < 16; ++r) {
      const int row = (r & 3) + 8 * (r >> 2) + rb;
      out[(m0 + row) * D_H + c] = ((float)A[r] + bb - mmc) * inv + bec;
    }
  }
}

extern "C" void kernel_launch(void* const* d_in, const int* in_sizes, int n_in,
                              void* d_out, int out_size, void* d_ws, size_t ws_size,
                              hipStream_t stream) {
  const float* X    = (const float*)d_in[0];  // [32768, 2048]
  const float* W    = (const float*)d_in[1];  // [2048, 512]
  const float* b    = (const float*)d_in[2];  // [512]
  const float* beta = (const float*)d_in[3];  // [512]
  const float* mm   = (const float*)d_in[4];  // [512]
  const float* mv   = (const float*)d_in[5];  // [512]
  float* out = (float*)d_out;                 // [32768, 512]

  char* Wt = (char*)d_ws;  // [512][2048] i8 = 1 MB

  pack_wt_kernel<<<dim3(D_IN / 32), dim3(D_H), 0, stream>>>(W, Wt);

  const int M = in_sizes[0] / D_IN;  // 32768
  bgemm_kernel<<<dim3(M / BM), dim3(256), 0, stream>>>(X, Wt, b, beta, mm, mv, out);
}